// Round 17
// baseline (113.149 us; speedup 1.0000x reference)
//
#include <hip/hip_runtime.h>
#include <hip/hip_bf16.h>

#define N_NODES 100000
#define N_EDGES 1600000
#define FEAT 128
#define NBINS 4096
#define NBINS_USED 4000         // 4000*25 = 100000 exact
#define BIN_NODES 25
#define PBLK 250                // partition blocks (each owns CHUNK edges)
#define CHUNK (N_EDGES / PBLK)  // 6400 (exact)
#define NTBL (NBINS + 1)
#define CSR_MAX 768             // per-bin edges: mean 400, +18 sigma
#define PREP_BLOCKS (N_NODES * FEAT / 8 / 512)  // 3125 (exact)
#define WCONV_BLOCKS 8          // weight bf16-conversion blocks

typedef __bf16 bf16x8 __attribute__((ext_vector_type(8)));
typedef unsigned short ushort8 __attribute__((ext_vector_type(8)));
typedef float f32x4 __attribute__((ext_vector_type(4)));
typedef float f32x2 __attribute__((ext_vector_type(2)));

__device__ __forceinline__ unsigned short f2bf_bits(float f) {
    unsigned u = __builtin_bit_cast(unsigned, f);
    unsigned r = (u + 0x7fffu + ((u >> 16) & 1u)) >> 16;
    return (unsigned short)r;
}

__device__ __forceinline__ ushort8 cvt8(float4 a, float4 b) {
    ushort8 u;
    u[0] = f2bf_bits(a.x); u[1] = f2bf_bits(a.y);
    u[2] = f2bf_bits(a.z); u[3] = f2bf_bits(a.w);
    u[4] = f2bf_bits(b.x); u[5] = f2bf_bits(b.y);
    u[6] = f2bf_bits(b.z); u[7] = f2bf_bits(b.w);
    return u;
}

// ---------------------------------------------------------------------------
// 1) fused prep + partition + weight-conversion (role-split by blockIdx).
// ---------------------------------------------------------------------------
__global__ __launch_bounds__(512) void preppart_kernel(
    const float* __restrict__ x, unsigned short* __restrict__ xbf,
    unsigned int* __restrict__ x8, const int* __restrict__ ei,
    int* __restrict__ offtbl, int* __restrict__ ebin,
    const float* __restrict__ Wl, const float* __restrict__ Wr,
    unsigned short* __restrict__ wlbf, unsigned short* __restrict__ wrbf) {
    __shared__ int h[NBINS];   // histogram, then cursors (global positions)
    __shared__ int wsum[8];
    const int tid = threadIdx.x;

    if (blockIdx.x >= PBLK + PREP_BLOCKS) {
        // ---- weight-conversion role: 32768 elems across Wl,Wr ----
        int t = (blockIdx.x - PBLK - PREP_BLOCKS) * 512 + tid;  // 0..4095
        const float* src;
        unsigned short* dst;
        int off;
        if (t < 2048) { src = Wl; dst = wlbf; off = t * 8; }
        else          { src = Wr; dst = wrbf; off = (t - 2048) * 8; }
        float4 a = *(const float4*)(src + off);
        float4 b = *(const float4*)(src + off + 4);
        *(ushort8*)(dst + off) = cvt8(a, b);
        return;
    }

    if (blockIdx.x >= PBLK) {
        // ---- prep role ----
        int t = (blockIdx.x - PBLK) * 512 + tid;
        float4 a = ((const float4*)x)[t * 2];
        float4 b = ((const float4*)x)[t * 2 + 1];
        ((ushort8*)xbf)[t] = cvt8(a, b);
        int w0 = __builtin_amdgcn_cvt_pk_fp8_f32(a.x, a.y, 0, false);
        w0     = __builtin_amdgcn_cvt_pk_fp8_f32(a.z, a.w, w0, true);
        int w1 = __builtin_amdgcn_cvt_pk_fp8_f32(b.x, b.y, 0, false);
        w1     = __builtin_amdgcn_cvt_pk_fp8_f32(b.z, b.w, w1, true);
        uint2 p; p.x = (unsigned)w0; p.y = (unsigned)w1;
        ((uint2*)x8)[t] = p;
        return;
    }

    // ---- partition role ----
    const int b = blockIdx.x;
    const int lane = tid & 63, wid = tid >> 6;

    for (int i = tid; i < NBINS; i += 512) h[i] = 0;
    __syncthreads();

    const int4* dsts = (const int4*)(ei + N_EDGES + b * CHUNK);
    for (int i = tid; i < CHUNK / 4; i += 512) {
        int4 d = dsts[i];
        atomicAdd(&h[d.x / BIN_NODES], 1);
        atomicAdd(&h[d.y / BIN_NODES], 1);
        atomicAdd(&h[d.z / BIN_NODES], 1);
        atomicAdd(&h[d.w / BIN_NODES], 1);
    }
    __syncthreads();

    // in-block exclusive scan over 4096 counts (8 per thread)
    const int i0 = tid * 8;
    int v[8];
    int s = 0;
    #pragma unroll
    for (int j = 0; j < 8; ++j) { v[j] = h[i0 + j]; s += v[j]; }
    int incl = s;
    #pragma unroll
    for (int d = 1; d < 64; d <<= 1) {
        int up = __shfl_up(incl, d);
        if (lane >= d) incl += up;
    }
    if (lane == 63) wsum[wid] = incl;
    __syncthreads();
    if (tid == 0) {
        int run = 0;
        #pragma unroll
        for (int i = 0; i < 8; ++i) { int w = wsum[i]; wsum[i] = run; run += w; }
    }
    __syncthreads();
    int run = wsum[wid] + incl - s + b * CHUNK;   // global position
    int* otb = offtbl + (size_t)b * NTBL;
    #pragma unroll
    for (int j = 0; j < 8; ++j) {
        h[i0 + j] = run; otb[i0 + j] = run; run += v[j];
    }
    if (tid == 0) otb[NBINS] = (b + 1) * CHUNK;
    __syncthreads();

    // scatter pass: private, cursor-sequential writes
    const int4* srcs = (const int4*)(ei + b * CHUNK);
    for (int i = tid; i < CHUNK / 4; i += 512) {
        int4 s4 = srcs[i];
        int4 d4 = dsts[i];
        int bin, ln, pos;
        bin = d4.x / BIN_NODES; ln = d4.x - bin * BIN_NODES;
        pos = atomicAdd(&h[bin], 1); ebin[pos] = s4.x | (ln << 17);
        bin = d4.y / BIN_NODES; ln = d4.y - bin * BIN_NODES;
        pos = atomicAdd(&h[bin], 1); ebin[pos] = s4.y | (ln << 17);
        bin = d4.z / BIN_NODES; ln = d4.z - bin * BIN_NODES;
        pos = atomicAdd(&h[bin], 1); ebin[pos] = s4.z | (ln << 17);
        bin = d4.w / BIN_NODES; ln = d4.w - bin * BIN_NODES;
        pos = atomicAdd(&h[bin], 1); ebin[pos] = s4.w | (ln << 17);
    }
}

// ---------------------------------------------------------------------------
// 2) FUSED aggregation + GEMM, 25-node bins (small LDS -> full occupancy).
//    CSR build -> fp8 gather-mean -> xbar rows in LDS tile ->
//    MFMA @Wl^T -> restage x rows -> MFMA @Wr^T -> out = acc + bias.
// ---------------------------------------------------------------------------
#define ACC8(v)                                                             \
    {                                                                       \
        acc2[0] += __builtin_amdgcn_cvt_pk_f32_fp8((int)(v).x, false);      \
        acc2[1] += __builtin_amdgcn_cvt_pk_f32_fp8((int)(v).x, true);       \
        acc2[2] += __builtin_amdgcn_cvt_pk_f32_fp8((int)(v).y, false);      \
        acc2[3] += __builtin_amdgcn_cvt_pk_f32_fp8((int)(v).y, true);       \
    }

__global__ __launch_bounds__(256) void aggemm_kernel(
    const unsigned char* __restrict__ x8, const unsigned short* __restrict__ xbf,
    const int* __restrict__ offtbl, const int* __restrict__ ebin,
    const unsigned short* __restrict__ wlbf, const unsigned short* __restrict__ wrbf,
    const float* __restrict__ bl, float* __restrict__ out) {
    __shared__ int lcnt[BIN_NODES];
    __shared__ int loff[BIN_NODES];
    __shared__ int lcur[BIN_NODES];
    __shared__ int lraw[CSR_MAX];
    __shared__ int lcsr[CSR_MAX];
    __shared__ int wtot[4];
    __shared__ unsigned short lA[32][136];   // xbar tile, then x tile

    const int bid = blockIdx.x, tid = threadIdx.x;
    // XCD swizzle: XCD (bid&7) owns bins [(bid&7)*512, ...+512)
    const int b = (bid & 7) * (NBINS / 8) + (bid >> 3);
    if (b >= NBINS_USED) return;   // empty trailing bins

    const int lane = tid & 63, wave = tid >> 6;

    // this thread's run (one per partition block)
    int st = 0, L = 0;
    if (tid < PBLK) {
        st = offtbl[(size_t)tid * NTBL + b];
        L  = offtbl[(size_t)tid * NTBL + b + 1] - st;
    }
    if (tid < BIN_NODES) lcnt[tid] = 0;

    // 256-thread exclusive scan of run lengths -> LDS staging offset
    int incl = L;
    #pragma unroll
    for (int d = 1; d < 64; d <<= 1) {
        int up = __shfl_up(incl, d);
        if (lane >= d) incl += up;
    }
    if (lane == 63) wtot[wave] = incl;
    __syncthreads();
    int woff = 0;
    #pragma unroll
    for (int w = 0; w < 4; ++w) woff += (w < wave) ? wtot[w] : 0;
    const int pfx = woff + incl - L;

    // single global read of this bin's edges: copy to lraw + count
    for (int i = 0; i < L; ++i) {
        int v = ebin[st + i];
        lraw[pfx + i] = v;
        atomicAdd(&lcnt[v >> 17], 1);
    }
    __syncthreads();

    // exclusive scan of 25 counters in wave 0
    if (wave == 0) {
        int c = (lane < BIN_NODES) ? lcnt[lane] : 0;
        int ic = c;
        #pragma unroll
        for (int d = 1; d < 32; d <<= 1) {
            int up = __shfl_up(ic, d);
            if (lane >= d) ic += up;
        }
        if (lane < BIN_NODES) {
            loff[lane] = ic - c;
            lcur[lane] = ic - c;
        }
    }
    __syncthreads();

    // ln-scatter entirely from LDS
    for (int i = 0; i < L; ++i) {
        int v = lraw[pfx + i];
        int pos = atomicAdd(&lcur[v >> 17], 1);
        lcsr[pos] = v & 0x1FFFF;
    }
    __syncthreads();

    // fp8 gather-mean; xbar row (bf16) -> LDS tile
    const int g = lane >> 4;               // row group 0..3
    const unsigned c8 = (lane & 15) * 8;   // byte/ushort offset in a row
    for (int ln = wave; ln < BIN_NODES; ln += 4) {
        const int deg = lcnt[ln];
        const int off = loff[ln];
        f32x2 acc2[4];
        #pragma unroll
        for (int i = 0; i < 4; ++i) acc2[i] = (f32x2){0.f, 0.f};
        for (int base = 0; base < deg; base += 16) {
            int j0 = base + g, j1 = j0 + 4, j2 = j0 + 8, j3 = j0 + 12;
            bool pA = j0 < deg, pB = j1 < deg, pC = j2 < deg, pD = j3 < deg;
            unsigned sA = (unsigned)(pA ? lcsr[off + j0] : lcsr[off]);
            unsigned sB = (unsigned)(pB ? lcsr[off + j1] : lcsr[off]);
            unsigned sC = (unsigned)(pC ? lcsr[off + j2] : lcsr[off]);
            unsigned sD = (unsigned)(pD ? lcsr[off + j3] : lcsr[off]);
            uint2 va = *(const uint2*)(x8 + ((sA << 7) + c8));
            uint2 vb = *(const uint2*)(x8 + ((sB << 7) + c8));
            uint2 vc = *(const uint2*)(x8 + ((sC << 7) + c8));
            uint2 vd = *(const uint2*)(x8 + ((sD << 7) + c8));
            if (pA) ACC8(va);
            if (pB) ACC8(vb);
            if (pC) ACC8(vc);
            if (pD) ACC8(vd);
        }
        #pragma unroll
        for (int i = 0; i < 4; ++i) {
            #pragma unroll
            for (int k = 0; k < 2; ++k) {
                acc2[i][k] += __shfl_xor(acc2[i][k], 16);
                acc2[i][k] += __shfl_xor(acc2[i][k], 32);
            }
        }
        if (lane < 16) {
            float inv = 1.0f / (float)(deg > 0 ? deg : 1);
            ushort8 o;
            #pragma unroll
            for (int i = 0; i < 4; ++i) {
                o[2 * i]     = f2bf_bits(acc2[i][0] * inv);
                o[2 * i + 1] = f2bf_bits(acc2[i][1] * inv);
            }
            *(ushort8*)&lA[ln][c8] = o;
        }
    }
    __syncthreads();

    // ---- in-block GEMM. wave owns cols [wave*32, wave*32+32) ----
    const int l15 = lane & 15, lhi = lane >> 4;
    const int colbase = wave * 32;
    f32x4 acc[2][2];
    #pragma unroll
    for (int rh = 0; rh < 2; ++rh)
        #pragma unroll
        for (int ct = 0; ct < 2; ++ct) acc[rh][ct] = (f32x4){0.f, 0.f, 0.f, 0.f};

    float biasv[2];
    {
        // phase 1: acc += xbarTile @ Wl^T  (rows 25..31 are garbage, unstored)
        bf16x8 bW[2][4];
        #pragma unroll
        for (int ct = 0; ct < 2; ++ct) {
            int col = colbase + ct * 16 + l15;
            biasv[ct] = bl[col];
            #pragma unroll
            for (int s = 0; s < 4; ++s)
                bW[ct][s] = __builtin_bit_cast(bf16x8, *(const ushort8*)(wlbf + col * 128 + lhi * 8 + s * 32));
        }
        #pragma unroll
        for (int rh = 0; rh < 2; ++rh) {
            int arow = rh * 16 + l15;
            bf16x8 aF[4];
            #pragma unroll
            for (int s = 0; s < 4; ++s)
                aF[s] = __builtin_bit_cast(bf16x8, *(const ushort8*)&lA[arow][lhi * 8 + s * 32]);
            #pragma unroll
            for (int ct = 0; ct < 2; ++ct) {
                f32x4 a = acc[rh][ct];
                #pragma unroll
                for (int s = 0; s < 4; ++s)
                    a = __builtin_amdgcn_mfma_f32_16x16x32_bf16(aF[s], bW[ct][s], a, 0, 0, 0);
                acc[rh][ct] = a;
            }
        }
    }
    __syncthreads();   // all waves done reading xbar tile

    // restage lA with x rows (bf16) for the root transform
    {
        int r = tid >> 3;              // 0..31
        int c0 = (tid & 7) * 16;       // 0..112
        int n = b * BIN_NODES + r;
        if (n > N_NODES - 1) n = N_NODES - 1;
        const unsigned short* src = xbf + (size_t)n * FEAT + c0;
        *(ushort8*)&lA[r][c0]     = *(const ushort8*)(src);
        *(ushort8*)&lA[r][c0 + 8] = *(const ushort8*)(src + 8);
    }
    __syncthreads();

    {
        // phase 2: acc += xTile @ Wr^T
        bf16x8 bW[2][4];
        #pragma unroll
        for (int ct = 0; ct < 2; ++ct) {
            int col = colbase + ct * 16 + l15;
            #pragma unroll
            for (int s = 0; s < 4; ++s)
                bW[ct][s] = __builtin_bit_cast(bf16x8, *(const ushort8*)(wrbf + col * 128 + lhi * 8 + s * 32));
        }
        #pragma unroll
        for (int rh = 0; rh < 2; ++rh) {
            int arow = rh * 16 + l15;
            bf16x8 aF[4];
            #pragma unroll
            for (int s = 0; s < 4; ++s)
                aF[s] = __builtin_bit_cast(bf16x8, *(const ushort8*)&lA[arow][lhi * 8 + s * 32]);
            #pragma unroll
            for (int ct = 0; ct < 2; ++ct) {
                f32x4 a = acc[rh][ct];
                #pragma unroll
                for (int s = 0; s < 4; ++s)
                    a = __builtin_amdgcn_mfma_f32_16x16x32_bf16(aF[s], bW[ct][s], a, 0, 0, 0);
                acc[rh][ct] = a;
            }
        }
    }

    // epilogue: out = acc + bias*[deg>0], rows < BIN_NODES only
    #pragma unroll
    for (int rh = 0; rh < 2; ++rh)
        #pragma unroll
        for (int ct = 0; ct < 2; ++ct) {
            int col = colbase + ct * 16 + l15;
            #pragma unroll
            for (int j = 0; j < 4; ++j) {
                int rl = rh * 16 + lhi * 4 + j;
                if (rl < BIN_NODES) {
                    int n = b * BIN_NODES + rl;
                    float bias = (lcnt[rl] > 0) ? biasv[ct] : 0.f;
                    out[(size_t)n * FEAT + col] = acc[rh][ct][j] + bias;
                }
            }
        }
}

extern "C" void kernel_launch(void* const* d_in, const int* in_sizes, int n_in,
                              void* d_out, int out_size, void* d_ws, size_t ws_size,
                              hipStream_t stream) {
    const float* x  = (const float*)d_in[0];
    const int*   ei = (const int*)d_in[1];
    const float* Wl = (const float*)d_in[2];
    const float* bl = (const float*)d_in[3];
    const float* Wr = (const float*)d_in[4];
    float* out = (float*)d_out;

    unsigned short* xbf = (unsigned short*)d_ws;                     // 25.6 MB
    unsigned int* x8    = (unsigned int*)(xbf + (size_t)N_NODES * FEAT); // 12.8 MB
    int* offtbl = (int*)(x8 + (size_t)N_NODES * FEAT / 4);           // 4.1 MB
    unsigned short* wlbf = (unsigned short*)(offtbl + (size_t)PBLK * NTBL); // 32 KB
    unsigned short* wrbf = wlbf + 16384;                             // 32 KB
    int* ebin   = (int*)(wrbf + 16384);                              // 6.4 MB

    preppart_kernel<<<PBLK + PREP_BLOCKS + WCONV_BLOCKS, 512, 0, stream>>>(
        x, xbf, x8, ei, offtbl, ebin, Wl, Wr, wlbf, wrbf);
    aggemm_kernel<<<NBINS, 256, 0, stream>>>((const unsigned char*)x8, xbf,
                                             offtbl, ebin, wlbf, wrbf, bl, out);
}

// Round 18
// 89.884 us; speedup vs baseline: 1.2588x; 1.2588x over previous
//
#include <hip/hip_runtime.h>
#include <hip/hip_bf16.h>

#define N_NODES 100000
#define N_EDGES 1600000
#define FEAT 128
#define NBINS 2048
#define BIN_NODES 49            // 2048*49 = 100352 >= 100000
#define PBLK 250                // partition blocks (each owns CHUNK edges)
#define CHUNK (N_EDGES / PBLK)  // 6400 (exact)
#define NTBL (NBINS + 1)
#define CSR_MAX 1280            // per-bin edges: mean 784, +17 sigma
#define PREP_BLOCKS (N_NODES * FEAT / 8 / 512)  // 3125 (exact)
#define WCONV_BLOCKS 8          // weight bf16-conversion blocks

typedef __bf16 bf16x8 __attribute__((ext_vector_type(8)));
typedef unsigned short ushort8 __attribute__((ext_vector_type(8)));
typedef float f32x4 __attribute__((ext_vector_type(4)));
typedef float f32x2 __attribute__((ext_vector_type(2)));

__device__ __forceinline__ unsigned short f2bf_bits(float f) {
    unsigned u = __builtin_bit_cast(unsigned, f);
    unsigned r = (u + 0x7fffu + ((u >> 16) & 1u)) >> 16;
    return (unsigned short)r;
}

__device__ __forceinline__ ushort8 cvt8(float4 a, float4 b) {
    ushort8 u;
    u[0] = f2bf_bits(a.x); u[1] = f2bf_bits(a.y);
    u[2] = f2bf_bits(a.z); u[3] = f2bf_bits(a.w);
    u[4] = f2bf_bits(b.x); u[5] = f2bf_bits(b.y);
    u[6] = f2bf_bits(b.z); u[7] = f2bf_bits(b.w);
    return u;
}

// ---------------------------------------------------------------------------
// 1) fused prep + partition + weight-conversion (role-split by blockIdx).
// ---------------------------------------------------------------------------
__global__ __launch_bounds__(512) void preppart_kernel(
    const float* __restrict__ x, unsigned short* __restrict__ xbf,
    unsigned int* __restrict__ x8, const int* __restrict__ ei,
    int* __restrict__ offtbl, int* __restrict__ ebin,
    const float* __restrict__ Wl, const float* __restrict__ Wr,
    unsigned short* __restrict__ wlbf, unsigned short* __restrict__ wrbf) {
    __shared__ int h[NBINS];   // histogram, then cursors (global positions)
    __shared__ int wsum[8];
    const int tid = threadIdx.x;

    if (blockIdx.x >= PBLK + PREP_BLOCKS) {
        // ---- weight-conversion role: 32768 elems across Wl,Wr ----
        int t = (blockIdx.x - PBLK - PREP_BLOCKS) * 512 + tid;  // 0..4095
        const float* src;
        unsigned short* dst;
        int off;
        if (t < 2048) { src = Wl; dst = wlbf; off = t * 8; }
        else          { src = Wr; dst = wrbf; off = (t - 2048) * 8; }
        float4 a = *(const float4*)(src + off);
        float4 b = *(const float4*)(src + off + 4);
        *(ushort8*)(dst + off) = cvt8(a, b);
        return;
    }

    if (blockIdx.x >= PBLK) {
        // ---- prep role ----
        int t = (blockIdx.x - PBLK) * 512 + tid;
        float4 a = ((const float4*)x)[t * 2];
        float4 b = ((const float4*)x)[t * 2 + 1];
        ((ushort8*)xbf)[t] = cvt8(a, b);
        int w0 = __builtin_amdgcn_cvt_pk_fp8_f32(a.x, a.y, 0, false);
        w0     = __builtin_amdgcn_cvt_pk_fp8_f32(a.z, a.w, w0, true);
        int w1 = __builtin_amdgcn_cvt_pk_fp8_f32(b.x, b.y, 0, false);
        w1     = __builtin_amdgcn_cvt_pk_fp8_f32(b.z, b.w, w1, true);
        uint2 p; p.x = (unsigned)w0; p.y = (unsigned)w1;
        ((uint2*)x8)[t] = p;
        return;
    }

    // ---- partition role ----
    const int b = blockIdx.x;
    const int lane = tid & 63, wid = tid >> 6;

    for (int i = tid; i < NBINS; i += 512) h[i] = 0;
    __syncthreads();

    const int4* dsts = (const int4*)(ei + N_EDGES + b * CHUNK);
    for (int i = tid; i < CHUNK / 4; i += 512) {
        int4 d = dsts[i];
        atomicAdd(&h[d.x / BIN_NODES], 1);
        atomicAdd(&h[d.y / BIN_NODES], 1);
        atomicAdd(&h[d.z / BIN_NODES], 1);
        atomicAdd(&h[d.w / BIN_NODES], 1);
    }
    __syncthreads();

    // in-block exclusive scan over 2048 counts (4 per thread)
    const int i0 = tid * 4;
    int v0 = h[i0], v1 = h[i0 + 1], v2 = h[i0 + 2], v3 = h[i0 + 3];
    const int s = v0 + v1 + v2 + v3;
    int incl = s;
    #pragma unroll
    for (int d = 1; d < 64; d <<= 1) {
        int up = __shfl_up(incl, d);
        if (lane >= d) incl += up;
    }
    if (lane == 63) wsum[wid] = incl;
    __syncthreads();
    if (tid == 0) {
        int run = 0;
        #pragma unroll
        for (int i = 0; i < 8; ++i) { int v = wsum[i]; wsum[i] = run; run += v; }
    }
    __syncthreads();
    int run = wsum[wid] + incl - s + b * CHUNK;   // global position
    int* otb = offtbl + (size_t)b * NTBL;
    h[i0] = run; otb[i0] = run; run += v0;
    h[i0 + 1] = run; otb[i0 + 1] = run; run += v1;
    h[i0 + 2] = run; otb[i0 + 2] = run; run += v2;
    h[i0 + 3] = run; otb[i0 + 3] = run; run += v3;
    if (tid == 0) otb[NBINS] = (b + 1) * CHUNK;
    __syncthreads();

    // scatter pass: private, cursor-sequential writes
    const int4* srcs = (const int4*)(ei + b * CHUNK);
    for (int i = tid; i < CHUNK / 4; i += 512) {
        int4 s4 = srcs[i];
        int4 d4 = dsts[i];
        int bin, ln, pos;
        bin = d4.x / BIN_NODES; ln = d4.x - bin * BIN_NODES;
        pos = atomicAdd(&h[bin], 1); ebin[pos] = s4.x | (ln << 17);
        bin = d4.y / BIN_NODES; ln = d4.y - bin * BIN_NODES;
        pos = atomicAdd(&h[bin], 1); ebin[pos] = s4.y | (ln << 17);
        bin = d4.z / BIN_NODES; ln = d4.z - bin * BIN_NODES;
        pos = atomicAdd(&h[bin], 1); ebin[pos] = s4.z | (ln << 17);
        bin = d4.w / BIN_NODES; ln = d4.w - bin * BIN_NODES;
        pos = atomicAdd(&h[bin], 1); ebin[pos] = s4.w | (ln << 17);
    }
}

// ---------------------------------------------------------------------------
// 2) per-bin aggregation. 16 lanes x uint2 per row; single 16-row loop with
//    4 predicated independent loads per iteration (measured-best MLP=4).
// ---------------------------------------------------------------------------
#define ACC8(v)                                                             \
    {                                                                       \
        acc2[0] += __builtin_amdgcn_cvt_pk_f32_fp8((int)(v).x, false);      \
        acc2[1] += __builtin_amdgcn_cvt_pk_f32_fp8((int)(v).x, true);       \
        acc2[2] += __builtin_amdgcn_cvt_pk_f32_fp8((int)(v).y, false);      \
        acc2[3] += __builtin_amdgcn_cvt_pk_f32_fp8((int)(v).y, true);       \
    }

__global__ __launch_bounds__(256) void agg_kernel(
    const unsigned char* __restrict__ x8, const int* __restrict__ offtbl,
    const int* __restrict__ ebin, unsigned short* __restrict__ xbarbf,
    int* __restrict__ degs) {
    __shared__ int lcnt[BIN_NODES];
    __shared__ int loff[BIN_NODES];
    __shared__ int lcur[BIN_NODES];
    __shared__ int lraw[CSR_MAX];
    __shared__ int lcsr[CSR_MAX];
    __shared__ int wtot[4];

    const int bid = blockIdx.x, tid = threadIdx.x;
    // XCD swizzle: XCD (bid&7) owns bins [(bid&7)*256, ...+256)
    const int b = (bid & 7) * (NBINS / 8) + (bid >> 3);
    int nb = N_NODES - b * BIN_NODES;
    if (nb <= 0) return;          // empty trailing bins
    if (nb > BIN_NODES) nb = BIN_NODES;

    const int lane = tid & 63, wave = tid >> 6;

    // this thread's run (one per partition block)
    int st = 0, L = 0;
    if (tid < PBLK) {
        st = offtbl[(size_t)tid * NTBL + b];
        L  = offtbl[(size_t)tid * NTBL + b + 1] - st;
    }
    if (tid < BIN_NODES) lcnt[tid] = 0;

    // 256-thread exclusive scan of run lengths -> LDS staging offset
    int incl = L;
    #pragma unroll
    for (int d = 1; d < 64; d <<= 1) {
        int up = __shfl_up(incl, d);
        if (lane >= d) incl += up;
    }
    if (lane == 63) wtot[wave] = incl;
    __syncthreads();
    int woff = 0;
    #pragma unroll
    for (int w = 0; w < 4; ++w) woff += (w < wave) ? wtot[w] : 0;
    const int pfx = woff + incl - L;

    // single global read of this bin's edges: copy to lraw + count
    for (int i = 0; i < L; ++i) {
        int v = ebin[st + i];
        lraw[pfx + i] = v;
        atomicAdd(&lcnt[v >> 17], 1);
    }
    __syncthreads();

    // exclusive scan of 49 counters in wave 0
    if (wave == 0) {
        int c = (lane < BIN_NODES) ? lcnt[lane] : 0;
        int ic = c;
        #pragma unroll
        for (int d = 1; d < 64; d <<= 1) {
            int up = __shfl_up(ic, d);
            if (lane >= d) ic += up;
        }
        if (lane < BIN_NODES) {
            loff[lane] = ic - c;
            lcur[lane] = ic - c;
        }
    }
    __syncthreads();

    // ln-scatter entirely from LDS
    for (int i = 0; i < L; ++i) {
        int v = lraw[pfx + i];
        int pos = atomicAdd(&lcur[v >> 17], 1);
        lcsr[pos] = v & 0x1FFFF;
    }
    __syncthreads();

    const int g = lane >> 4;               // row group 0..3
    const unsigned c8 = (lane & 15) * 8;   // byte offset in 128 B fp8 row
    for (int ln = wave; ln < nb; ln += 4) {
        const int deg = lcnt[ln];
        const int off = loff[ln];
        f32x2 acc2[4];
        #pragma unroll
        for (int i = 0; i < 4; ++i) acc2[i] = (f32x2){0.f, 0.f};
        // 16 rows / 4 independent predicated loads per iteration
        for (int base = 0; base < deg; base += 16) {
            int j0 = base + g, j1 = j0 + 4, j2 = j0 + 8, j3 = j0 + 12;
            bool pA = j0 < deg, pB = j1 < deg, pC = j2 < deg, pD = j3 < deg;
            unsigned sA = (unsigned)(pA ? lcsr[off + j0] : lcsr[off]);
            unsigned sB = (unsigned)(pB ? lcsr[off + j1] : lcsr[off]);
            unsigned sC = (unsigned)(pC ? lcsr[off + j2] : lcsr[off]);
            unsigned sD = (unsigned)(pD ? lcsr[off + j3] : lcsr[off]);
            uint2 va = *(const uint2*)(x8 + ((sA << 7) + c8));
            uint2 vb = *(const uint2*)(x8 + ((sB << 7) + c8));
            uint2 vc = *(const uint2*)(x8 + ((sC << 7) + c8));
            uint2 vd = *(const uint2*)(x8 + ((sD << 7) + c8));
            if (pA) ACC8(va);
            if (pB) ACC8(vb);
            if (pC) ACC8(vc);
            if (pD) ACC8(vd);
        }
        #pragma unroll
        for (int i = 0; i < 4; ++i) {
            #pragma unroll
            for (int k = 0; k < 2; ++k) {
                acc2[i][k] += __shfl_xor(acc2[i][k], 16);
                acc2[i][k] += __shfl_xor(acc2[i][k], 32);
            }
        }
        const int n = b * BIN_NODES + ln;
        if (lane < 16) {
            float inv = 1.0f / (float)(deg > 0 ? deg : 1);
            ushort8 o;
            #pragma unroll
            for (int i = 0; i < 4; ++i) {
                o[2 * i]     = f2bf_bits(acc2[i][0] * inv);
                o[2 * i + 1] = f2bf_bits(acc2[i][1] * inv);
            }
            *(ushort8*)(xbarbf + (size_t)n * FEAT + c8) = o;
        }
        if (lane == 0) degs[n] = deg;
    }
}

// ---------------------------------------------------------------------------
// 3) fused GEMM (bf16 weights preconverted) with XCD-affinity tile mapping.
// ---------------------------------------------------------------------------
__global__ __launch_bounds__(256) void gemm_kernel(
    const unsigned short* __restrict__ xbf, const unsigned short* __restrict__ xbarbf,
    const unsigned short* __restrict__ wlbf, const float* __restrict__ bl,
    const unsigned short* __restrict__ wrbf, const int* __restrict__ degs,
    float* __restrict__ out) {

    __shared__ unsigned short lM[32][136];
    __shared__ unsigned short lX[32][136];

    const int tid = threadIdx.x;
    const int wave = tid >> 6, lane = tid & 63;
    const int l15 = lane & 15, lhi = lane >> 4;
    const int colbase = wave * 32;

    bf16x8 bB[2][8];
    float biasv[2];
    #pragma unroll
    for (int ct = 0; ct < 2; ++ct) {
        int col = colbase + ct * 16 + l15;
        biasv[ct] = bl[col];
        #pragma unroll
        for (int s = 0; s < 4; ++s) {
            int kb = lhi * 8 + s * 32;
            bB[ct][s]     = __builtin_bit_cast(bf16x8, *(const ushort8*)(wlbf + col * 128 + kb));
            bB[ct][4 + s] = __builtin_bit_cast(bf16x8, *(const ushort8*)(wrbf + col * 128 + kb));
        }
    }

    // XCD-affinity: 3125 tiles over 8 XCDs; XCD x owns [tile0, tile0+cnt)
    const int xcd = blockIdx.x & 7;
    const int sub = blockIdx.x >> 3;            // 0..127
    const int tile0 = xcd * 390 + (xcd < 5 ? xcd : 5);
    const int cnt = (xcd < 5) ? 391 : 390;
    for (int t = sub; t < cnt; t += 128) {
        const int tile = tile0 + t;
        const int row0 = tile * 32;
        {
            int r = tid >> 3;
            int c0 = (tid & 7) * 16;
            const unsigned short* sm = xbarbf + (size_t)(row0 + r) * FEAT + c0;
            const unsigned short* sx = xbf + (size_t)(row0 + r) * FEAT + c0;
            *(ushort8*)&lM[r][c0]     = *(const ushort8*)(sm);
            *(ushort8*)&lM[r][c0 + 8] = *(const ushort8*)(sm + 8);
            *(ushort8*)&lX[r][c0]     = *(const ushort8*)(sx);
            *(ushort8*)&lX[r][c0 + 8] = *(const ushort8*)(sx + 8);
        }
        __syncthreads();

        f32x4 acc[2][2];
        #pragma unroll
        for (int rh = 0; rh < 2; ++rh)
            #pragma unroll
            for (int ct = 0; ct < 2; ++ct) acc[rh][ct] = (f32x4){0.f, 0.f, 0.f, 0.f};

        #pragma unroll
        for (int rh = 0; rh < 2; ++rh) {
            int arow = rh * 16 + l15;
            bf16x8 aM[4], aX[4];
            #pragma unroll
            for (int s = 0; s < 4; ++s) {
                aM[s] = __builtin_bit_cast(bf16x8, *(const ushort8*)&lM[arow][lhi * 8 + s * 32]);
                aX[s] = __builtin_bit_cast(bf16x8, *(const ushort8*)&lX[arow][lhi * 8 + s * 32]);
            }
            #pragma unroll
            for (int ct = 0; ct < 2; ++ct) {
                f32x4 a = acc[rh][ct];
                #pragma unroll
                for (int s = 0; s < 4; ++s)
                    a = __builtin_amdgcn_mfma_f32_16x16x32_bf16(aM[s], bB[ct][s], a, 0, 0, 0);
                #pragma unroll
                for (int s = 0; s < 4; ++s)
                    a = __builtin_amdgcn_mfma_f32_16x16x32_bf16(aX[s], bB[ct][4 + s], a, 0, 0, 0);
                acc[rh][ct] = a;
            }
        }

        #pragma unroll
        for (int rh = 0; rh < 2; ++rh)
            #pragma unroll
            for (int ct = 0; ct < 2; ++ct) {
                int col = colbase + ct * 16 + l15;
                #pragma unroll
                for (int j = 0; j < 4; ++j) {
                    int r = row0 + rh * 16 + lhi * 4 + j;
                    float bias = (degs[r] > 0) ? biasv[ct] : 0.f;
                    out[(size_t)r * FEAT + col] = acc[rh][ct][j] + bias;
                }
            }
        __syncthreads();
    }
}

extern "C" void kernel_launch(void* const* d_in, const int* in_sizes, int n_in,
                              void* d_out, int out_size, void* d_ws, size_t ws_size,
                              hipStream_t stream) {
    const float* x  = (const float*)d_in[0];
    const int*   ei = (const int*)d_in[1];
    const float* Wl = (const float*)d_in[2];
    const float* bl = (const float*)d_in[3];
    const float* Wr = (const float*)d_in[4];
    float* out = (float*)d_out;

    unsigned short* xbf    = (unsigned short*)d_ws;                  // 25.6 MB
    unsigned short* xbarbf = xbf + (size_t)N_NODES * FEAT;           // 25.6 MB
    unsigned int* x8       = (unsigned int*)(xbarbf + (size_t)N_NODES * FEAT); // 12.8 MB
    int* degs   = (int*)(x8 + (size_t)N_NODES * FEAT / 4);           // 400 KB
    int* offtbl = degs + N_NODES;                                    // 2.05 MB
    unsigned short* wlbf = (unsigned short*)(offtbl + (size_t)PBLK * NTBL); // 32 KB
    unsigned short* wrbf = wlbf + 16384;                             // 32 KB
    int* ebin   = (int*)(wrbf + 16384);                              // 6.4 MB

    preppart_kernel<<<PBLK + PREP_BLOCKS + WCONV_BLOCKS, 512, 0, stream>>>(
        x, xbf, x8, ei, offtbl, ebin, Wl, Wr, wlbf, wrbf);
    agg_kernel<<<NBINS, 256, 0, stream>>>((const unsigned char*)x8, offtbl, ebin, xbarbf, degs);
    gemm_kernel<<<1024, 256, 0, stream>>>(xbf, xbarbf, wlbf, bl, wrbf, degs, out);
}